// Round 12
// baseline (178.612 us; speedup 1.0000x reference)
//
#include <hip/hip_runtime.h>
#include <math.h>

#define HH 1024
#define VV 50257
#define NBLK 1024          // fused blocks (512 thr, 8 waves each)
#define NW (NBLK * 8)      // 8192 logits waves
#define TB (6 * NW)        // 49152
#define NTL (VV - TB)      // 1105 tail rows

__device__ __forceinline__ void lse_comb(float& m, float& s, float om, float os) {
    float M = fmaxf(m, om);
    s = s * __expf(m - M) + os * __expf(om - M);
    m = M;
}
__device__ __forceinline__ float sigmoidf(float x) { return 1.0f / (1.0f + __expf(-x)); }
__device__ __forceinline__ float dot4(float4 a, float4 b) {
    return a.x * b.x + a.y * b.y + a.z * b.z + a.w * b.w;
}

// Fused gates+cell+logits+LSE. All 1024 blocks co-resident (4/CU by LDS,
// VGPR capped 64). Device-scope counter sync: relaxed poll + single acquire.
__global__ __launch_bounds__(512, 8) void k_fused(
    const int* __restrict__ x, const float* __restrict__ emb,
    const float* __restrict__ h0, const float* __restrict__ c0,
    const float* __restrict__ w_ih, const float* __restrict__ w_hh,
    const float* __restrict__ b_ih, const float* __restrict__ b_hh,
    const float* __restrict__ w_out, const float* __restrict__ b_out,
    float* __restrict__ out, float* __restrict__ hbuf,
    float* __restrict__ logits, float* __restrict__ pm, float* __restrict__ ps,
    unsigned int* __restrict__ ctr) {
    __shared__ float4 pre[2048];   // 32 KB: wave w's c=0 row at pre[w*256..]
    __shared__ float4 hs4[256];    // 4 KB h
    __shared__ float sg2[8], sm[8], ss[8];
    const int tid = threadIdx.x;
    const int w = tid >> 6;
    const int lane = tid & 63;
    const int j = blockIdx.x;          // hidden index for gate phase
    const int widl = blockIdx.x * 8 + w;  // logits wave id 0..8191

    // ---- issue async prefetch of this wave's c=0 w_out row into LDS ----
    {
        const float* prow = w_out + (size_t)widl * HH;
#pragma unroll
        for (int i = 0; i < 4; ++i) {
            auto* gsrc = (const __attribute__((address_space(1))) unsigned int*)
                             (const void*)(prow + i * 256 + lane * 4);
            auto* ldst = (__attribute__((address_space(3))) unsigned int*)
                             (void*)(&pre[w * 256 + i * 64]);
            __builtin_amdgcn_global_load_lds(gsrc, ldst, 16, 0, 0);
        }
    }

    // ---- phase A: gates + cell (R9-proven form) ----
    {
        const int g = w >> 1, hf = w & 1;
        const int row = g * HH + j;
        const int base = hf * 512 + lane * 8;
        const float* e  = emb + (size_t)x[0] * HH + base;
        const float* wi = w_ih + (size_t)row * HH + base;
        const float* wh = w_hh + (size_t)row * HH + base;
        const float* hp = h0 + base;
        float4 wi0 = *reinterpret_cast<const float4*>(wi);
        float4 wi1 = *reinterpret_cast<const float4*>(wi + 4);
        float4 wh0 = *reinterpret_cast<const float4*>(wh);
        float4 wh1 = *reinterpret_cast<const float4*>(wh + 4);
        float4 e0  = *reinterpret_cast<const float4*>(e);
        float4 e1  = *reinterpret_cast<const float4*>(e + 4);
        float4 hv0 = *reinterpret_cast<const float4*>(hp);
        float4 hv1 = *reinterpret_cast<const float4*>(hp + 4);
        e0.x = fmaxf(e0.x, 0.f); e0.y = fmaxf(e0.y, 0.f);
        e0.z = fmaxf(e0.z, 0.f); e0.w = fmaxf(e0.w, 0.f);
        e1.x = fmaxf(e1.x, 0.f); e1.y = fmaxf(e1.y, 0.f);
        e1.z = fmaxf(e1.z, 0.f); e1.w = fmaxf(e1.w, 0.f);
        float acc = dot4(wi0, e0) + dot4(wi1, e1) + dot4(wh0, hv0) + dot4(wh1, hv1);
#pragma unroll
        for (int off = 1; off < 64; off <<= 1) acc += __shfl_xor(acc, off, 64);
        if (lane == 0)
            sg2[w] = acc + (hf == 0 ? b_ih[row] + b_hh[row] : 0.0f);
    }
    __syncthreads();
    if (tid == 0) {
        float ig = sigmoidf(sg2[0] + sg2[1]);
        float fg = sigmoidf(sg2[2] + sg2[3]);
        float gg = tanhf(sg2[4] + sg2[5]);
        float og = sigmoidf(sg2[6] + sg2[7]);
        float c = fg * c0[j] + ig * gg;
        float h = og * tanhf(c);
        hbuf[j] = h;
        out[VV + j] = h;
        out[VV + HH + j] = c;
        __threadfence();
        __hip_atomic_fetch_add(ctr, 1u, __ATOMIC_RELEASE, __HIP_MEMORY_SCOPE_AGENT);
        // relaxed poll (NO per-iteration invalidate), then one acquire
        while (__hip_atomic_load(ctr, __ATOMIC_RELAXED, __HIP_MEMORY_SCOPE_AGENT) < (unsigned)NBLK)
            __builtin_amdgcn_s_sleep(8);
        (void)__hip_atomic_load(ctr, __ATOMIC_ACQUIRE, __HIP_MEMORY_SCOPE_AGENT);
    }
    __syncthreads();
    if (tid < 256) hs4[tid] = reinterpret_cast<const float4*>(hbuf)[tid];
    __syncthreads();

    // ---- phase B: logits + online LSE (R9-proven form; c=0 from LDS) ----
    const int halfid = lane >> 5;
    const int hl = lane & 31;
    float m = -1e30f, s = 0.0f;
    asm volatile("s_waitcnt vmcnt(0)" ::: "memory");  // prefetch definitely landed

    {   // c = 0 from LDS (full-wave)
        float acc = 0.0f;
#pragma unroll
        for (int i = 0; i < 4; ++i)
            acc += dot4(pre[w * 256 + lane + 64 * i], hs4[lane + 64 * i]);
#pragma unroll
        for (int off = 1; off < 64; off <<= 1) acc += __shfl_xor(acc, off, 64);
        float v = acc + b_out[widl];
        if (lane == 0) logits[widl] = v;
        float vv = halfid ? -1e30f : v;   // count full-wave row in half 0 only
        float M = fmaxf(m, vv);
        s = s * __expf(m - M) + __expf(vv - M);
        m = M;
    }
    // c = 1..4: two half-wave pairs
#pragma unroll
    for (int k = 0; k < 2; ++k) {
        const int r = widl + (1 + 2 * k + halfid) * NW;
        const float* p = w_out + (size_t)r * HH + hl * 4;
        float acc = 0.0f;
#pragma unroll
        for (int jj = 0; jj < 8; ++jj)
            acc += dot4(*reinterpret_cast<const float4*>(p + jj * 128), hs4[hl + 32 * jj]);
#pragma unroll
        for (int off = 1; off < 32; off <<= 1) acc += __shfl_xor(acc, off, 64);
        const float v = acc + b_out[r];
        if (hl == 0) logits[r] = v;
        float M = fmaxf(m, v);
        s = s * __expf(m - M) + __expf(v - M);
        m = M;
    }
    {   // c = 5 full-wave
        const int r = widl + 5 * NW;
        const float* p = w_out + (size_t)r * HH + lane * 4;
        float acc = 0.0f;
#pragma unroll
        for (int i = 0; i < 4; ++i)
            acc += dot4(*reinterpret_cast<const float4*>(p + i * 256), hs4[lane + 64 * i]);
#pragma unroll
        for (int off = 1; off < 64; off <<= 1) acc += __shfl_xor(acc, off, 64);
        float v = acc + b_out[r];
        if (lane == 0) logits[r] = v;
        float vv = halfid ? -1e30f : v;
        float M = fmaxf(m, vv);
        s = s * __expf(m - M) + __expf(vv - M);
        m = M;
    }
    if (widl < NTL) {  // tail full-wave
        const int r = TB + widl;
        const float* p = w_out + (size_t)r * HH + lane * 4;
        float acc = 0.0f;
#pragma unroll
        for (int i = 0; i < 4; ++i)
            acc += dot4(*reinterpret_cast<const float4*>(p + i * 256), hs4[lane + 64 * i]);
#pragma unroll
        for (int off = 1; off < 64; off <<= 1) acc += __shfl_xor(acc, off, 64);
        float v = acc + b_out[r];
        if (lane == 0) logits[r] = v;
        float vv = halfid ? -1e30f : v;
        float M = fmaxf(m, vv);
        s = s * __expf(m - M) + __expf(vv - M);
        m = M;
    }

    // merge halves, then block combine over 8 waves
    {
        float om = __shfl_xor(m, 32, 64);
        float os = __shfl_xor(s, 32, 64);
        lse_comb(m, s, om, os);
    }
    if (lane == 0) { sm[w] = m; ss[w] = s; }
    __syncthreads();
    if (tid == 0) {
        float M = sm[0], S = ss[0];
#pragma unroll
        for (int q = 1; q < 8; ++q) lse_comb(M, S, sm[q], ss[q]);
        pm[blockIdx.x] = M;
        ps[blockIdx.x] = S;
    }
}

// k_final: fold the 1024 (m,s) pairs -> Z, subtract.
__global__ __launch_bounds__(256) void k_final(
    const float* __restrict__ logits, const float* __restrict__ pm,
    const float* __restrict__ ps, float* __restrict__ out) {
    __shared__ float sm[4], ss[4];
    __shared__ float sZ;
    int tid = threadIdx.x;
    int lane = tid & 63;
    float m = -1e30f, s = 0.0f;
#pragma unroll
    for (int t = 0; t < NBLK / 256; ++t) {
        int p = tid + t * 256;
        lse_comb(m, s, pm[p], ps[p]);
    }
#pragma unroll
    for (int off = 1; off < 64; off <<= 1) {
        float om = __shfl_xor(m, off, 64);
        float os = __shfl_xor(s, off, 64);
        lse_comb(m, s, om, os);
    }
    if (lane == 0) { sm[tid >> 6] = m; ss[tid >> 6] = s; }
    __syncthreads();
    if (tid == 0) {
        float M = sm[0], S = ss[0];
#pragma unroll
        for (int q = 1; q < 4; ++q) lse_comb(M, S, sm[q], ss[q]);
        sZ = M + logf(S);
    }
    __syncthreads();
    float Z = sZ;
    for (int i = blockIdx.x * 256 + tid; i < VV; i += gridDim.x * 256)
        out[i] = logits[i] - Z;
}

extern "C" void kernel_launch(void* const* d_in, const int* in_sizes, int n_in,
                              void* d_out, int out_size, void* d_ws, size_t ws_size,
                              hipStream_t stream) {
    const int*   x     = (const int*)d_in[0];
    const float* h0    = (const float*)d_in[1];
    const float* c0    = (const float*)d_in[2];
    const float* emb   = (const float*)d_in[3];
    const float* w_ih  = (const float*)d_in[4];
    const float* w_hh  = (const float*)d_in[5];
    const float* b_ih  = (const float*)d_in[6];
    const float* b_hh  = (const float*)d_in[7];
    const float* w_out = (const float*)d_in[8];
    const float* b_out = (const float*)d_in[9];
    float* out = (float*)d_out;
    float* ws  = (float*)d_ws;

    float* hbuf   = ws;                         // 1024
    float* logits = ws + 1024;                  // 50304 (padded)
    float* pm     = ws + 1024 + 50304;          // 1024
    float* ps     = pm + NBLK;                  // 1024
    unsigned int* ctr = (unsigned int*)(ps + NBLK);  // 1 u32 (256B-aligned)

    hipMemsetAsync(ctr, 0, sizeof(unsigned int), stream);
    k_fused<<<NBLK, 512, 0, stream>>>(x, emb, h0, c0, w_ih, w_hh, b_ih, b_hh,
                                      w_out, b_out, out, hbuf, logits, pm, ps, ctr);
    k_final<<<256, 256, 0, stream>>>(logits, pm, ps, out);
}

// Round 13
// 46.775 us; speedup vs baseline: 3.8185x; 3.8185x over previous
//
#include <hip/hip_runtime.h>
#include <math.h>

#define HH 1024
#define VV 50257
#define NLB 2048           // logits blocks
#define NWAVE (NLB * 4)    // 8192 logits waves
#define TBASE (6 * NWAVE)  // 49152; tail rows 49152..50256 (1105 rows)

__device__ __forceinline__ void lse_comb(float& m, float& s, float om, float os) {
    float M = fmaxf(m, om);
    s = s * __expf(m - M) + os * __expf(om - M);
    m = M;
}

__device__ __forceinline__ float sigmoidf(float x) { return 1.0f / (1.0f + __expf(-x)); }

__device__ __forceinline__ float dot4(float4 a, float4 b) {
    return a.x * b.x + a.y * b.y + a.z * b.z + a.w * b.w;
}

// Kernel 1: fused gates+cell. 1024 blocks x 512 threads (proven form).
__global__ __launch_bounds__(512) void k_gatecell(
    const int* __restrict__ x, const float* __restrict__ emb,
    const float* __restrict__ h0, const float* __restrict__ c0,
    const float* __restrict__ w_ih, const float* __restrict__ w_hh,
    const float* __restrict__ b_ih, const float* __restrict__ b_hh,
    float* __restrict__ out) {
    __shared__ float sg2[8];
    const int j = blockIdx.x;
    const int w = threadIdx.x >> 6;
    const int lane = threadIdx.x & 63;
    const int g = w >> 1, hf = w & 1;
    const int row = g * HH + j;
    const int base = hf * 512 + lane * 8;

    const float* e  = emb + (size_t)x[0] * HH + base;
    const float* wi = w_ih + (size_t)row * HH + base;
    const float* wh = w_hh + (size_t)row * HH + base;
    const float* hp = h0 + base;

    float4 wi0 = *reinterpret_cast<const float4*>(wi);
    float4 wi1 = *reinterpret_cast<const float4*>(wi + 4);
    float4 wh0 = *reinterpret_cast<const float4*>(wh);
    float4 wh1 = *reinterpret_cast<const float4*>(wh + 4);
    float4 e0  = *reinterpret_cast<const float4*>(e);
    float4 e1  = *reinterpret_cast<const float4*>(e + 4);
    float4 hv0 = *reinterpret_cast<const float4*>(hp);
    float4 hv1 = *reinterpret_cast<const float4*>(hp + 4);
    e0.x = fmaxf(e0.x, 0.f); e0.y = fmaxf(e0.y, 0.f);
    e0.z = fmaxf(e0.z, 0.f); e0.w = fmaxf(e0.w, 0.f);
    e1.x = fmaxf(e1.x, 0.f); e1.y = fmaxf(e1.y, 0.f);
    e1.z = fmaxf(e1.z, 0.f); e1.w = fmaxf(e1.w, 0.f);

    float acc = dot4(wi0, e0) + dot4(wi1, e1) + dot4(wh0, hv0) + dot4(wh1, hv1);
#pragma unroll
    for (int off = 1; off < 64; off <<= 1) acc += __shfl_xor(acc, off, 64);
    if (lane == 0)
        sg2[w] = acc + (hf == 0 ? b_ih[row] + b_hh[row] : 0.0f);
    __syncthreads();
    if (threadIdx.x == 0) {
        float ig = sigmoidf(sg2[0] + sg2[1]);
        float fg = sigmoidf(sg2[2] + sg2[3]);
        float gg = tanhf(sg2[4] + sg2[5]);
        float og = sigmoidf(sg2[6] + sg2[7]);
        float c = fg * c0[j] + ig * gg;
        float h = og * tanhf(c);
        out[VV + j] = h;
        out[VV + HH + j] = c;
    }
}

// Kernel 2: logits + fused per-block online LSE, HALF-WAVE row split:
// lanes 0-31 own row A, lanes 32-63 own row B. 8 load instrs per pair
// (1KB each), ONE 5-step xor reduce and ONE lanewise LSE update per pair.
__global__ __launch_bounds__(256, 8) void k_logits_lse(
    const float* __restrict__ w_out, const float* __restrict__ b_out,
    const float* __restrict__ h, float* __restrict__ logits,
    float* __restrict__ pm, float* __restrict__ ps) {
    __shared__ float4 hs4[256];
    __shared__ float sm[4], ss[4];
    const int tid = threadIdx.x;
    const int w = tid >> 6;
    const int lane = tid & 63;
    const int halfid = lane >> 5;   // 0: row A, 1: row B
    const int hl = lane & 31;

    hs4[tid] = reinterpret_cast<const float4*>(h)[tid];
    __syncthreads();

    const int wid = blockIdx.x * 4 + w;
    float m = -1e30f, s = 0.0f;

#pragma unroll
    for (int k = 0; k < 3; ++k) {
        const int r = wid + (2 * k + halfid) * NWAVE;   // my half's row
        const float* p = w_out + (size_t)r * HH + hl * 4;
        float acc = 0.0f;
#pragma unroll
        for (int j = 0; j < 8; ++j) {
            float4 wv = *reinterpret_cast<const float4*>(p + j * 128);
            acc += dot4(wv, hs4[hl + 32 * j]);
        }
#pragma unroll
        for (int off = 1; off < 32; off <<= 1) acc += __shfl_xor(acc, off, 64);
        const float v = acc + b_out[r];
        if (hl == 0) logits[r] = v;
        float M = fmaxf(m, v);            // branchless lanewise LSE
        s = s * __expf(m - M) + __expf(v - M);
        m = M;
    }
    // tail: rows TBASE..VV-1 (1105), two per wave on waves 0..552
    if (wid <= 552) {
        const int r = TBASE + 2 * wid + halfid;
        const bool valid = (r < VV);
        const int rc = valid ? r : (VV - 1);
        const float* p = w_out + (size_t)rc * HH + hl * 4;
        float acc = 0.0f;
#pragma unroll
        for (int j = 0; j < 8; ++j) {
            float4 wv = *reinterpret_cast<const float4*>(p + j * 128);
            acc += dot4(wv, hs4[hl + 32 * j]);
        }
#pragma unroll
        for (int off = 1; off < 32; off <<= 1) acc += __shfl_xor(acc, off, 64);
        float v = valid ? (acc + b_out[rc]) : -1e30f;
        if (hl == 0 && valid) logits[r] = v;
        float M = fmaxf(m, v);
        s = s * __expf(m - M) + __expf(v - M);
        m = M;
    }

    // merge the two halves (one cross-half combine), then block combine
    {
        float om = __shfl_xor(m, 32, 64);
        float os = __shfl_xor(s, 32, 64);
        lse_comb(m, s, om, os);
    }
    if (lane == 0) { sm[w] = m; ss[w] = s; }
    __syncthreads();
    if (tid == 0) {
        float M = sm[0], S = ss[0];
#pragma unroll
        for (int q = 1; q < 4; ++q) lse_comb(M, S, sm[q], ss[q]);
        pm[blockIdx.x] = M;
        ps[blockIdx.x] = S;
    }
}

// Kernel 3: each block redundantly folds the NLB (m,s) pairs -> Z, then
// grid-strides out[v] = logits[v] - Z.
__global__ __launch_bounds__(256) void k_final(
    const float* __restrict__ logits, const float* __restrict__ pm,
    const float* __restrict__ ps, float* __restrict__ out) {
    __shared__ float sm[4], ss[4];
    __shared__ float sZ;
    int tid = threadIdx.x;
    int lane = tid & 63;
    float m = -1e30f, s = 0.0f;
#pragma unroll
    for (int t = 0; t < NLB / 256; ++t) {
        int p = tid + t * 256;
        lse_comb(m, s, pm[p], ps[p]);
    }
#pragma unroll
    for (int off = 1; off < 64; off <<= 1) {
        float om = __shfl_xor(m, off, 64);
        float os = __shfl_xor(s, off, 64);
        lse_comb(m, s, om, os);
    }
    if (lane == 0) { sm[tid >> 6] = m; ss[tid >> 6] = s; }
    __syncthreads();
    if (tid == 0) {
        float M = sm[0], S = ss[0];
#pragma unroll
        for (int q = 1; q < 4; ++q) lse_comb(M, S, sm[q], ss[q]);
        sZ = M + logf(S);
    }
    __syncthreads();
    float Z = sZ;
    for (int i = blockIdx.x * 256 + tid; i < VV; i += gridDim.x * 256)
        out[i] = logits[i] - Z;
}

extern "C" void kernel_launch(void* const* d_in, const int* in_sizes, int n_in,
                              void* d_out, int out_size, void* d_ws, size_t ws_size,
                              hipStream_t stream) {
    const int*   x     = (const int*)d_in[0];
    const float* h0    = (const float*)d_in[1];
    const float* c0    = (const float*)d_in[2];
    const float* emb   = (const float*)d_in[3];
    const float* w_ih  = (const float*)d_in[4];
    const float* w_hh  = (const float*)d_in[5];
    const float* b_ih  = (const float*)d_in[6];
    const float* b_hh  = (const float*)d_in[7];
    const float* w_out = (const float*)d_in[8];
    const float* b_out = (const float*)d_in[9];
    float* out = (float*)d_out;
    float* ws  = (float*)d_ws;

    float* logits = ws;             // 50257 floats (pad to 50304)
    float* pm     = ws + 50304;     // NLB floats
    float* ps     = pm + NLB;       // NLB floats

    k_gatecell<<<HH, 512, 0, stream>>>(x, emb, h0, c0, w_ih, w_hh, b_ih, b_hh, out);
    k_logits_lse<<<NLB, 256, 0, stream>>>(w_out, b_out, out + VV, logits, pm, ps);
    k_final<<<256, 256, 0, stream>>>(logits, pm, ps, out);
}